// Round 3
// baseline (692.338 us; speedup 1.0000x reference)
//
#include <hip/hip_runtime.h>
#include <hip/hip_bf16.h>

typedef unsigned short ushort_t;
typedef unsigned int   uint_t;

typedef short    frag8  __attribute__((ext_vector_type(8)));   // 8 bf16 (4 VGPRs)
typedef float    f32x4  __attribute__((ext_vector_type(4)));
typedef ushort_t u16x8  __attribute__((ext_vector_type(8)));
typedef ushort_t u16x4  __attribute__((ext_vector_type(4)));

#define LOG2E 1.44269504088896340736f

constexpr int B_ = 4;
constexpr int C_ = 512;
constexpr int N_ = 4096;
constexpr int D_ = 64;    // CQK
constexpr int OROWS = 640; // 64 q + 64 k + 512 v
constexpr int JC_ = 8;     // j-chunks for attn_stats

__device__ __forceinline__ ushort_t f2bf(float f) {
    unsigned int x = __float_as_uint(f);
    unsigned int r = x + 0x7fffu + ((x >> 16) & 1u);
    return (ushort_t)(r >> 16);
}
__device__ __forceinline__ float bf2f(ushort_t h) {
    return __uint_as_float(((uint_t)h) << 16);
}

// ---------------- kernel 0: pack weights to bf16 hi (+ lo residual for q/k rows)
__global__ __launch_bounds__(256) void convw(const float* __restrict__ wq,
                                             const float* __restrict__ wk,
                                             const float* __restrict__ wv,
                                             ushort_t* __restrict__ Wb,
                                             ushort_t* __restrict__ Wlo) {
    int idx = (blockIdx.x * 256 + threadIdx.x) * 4;
    int row = idx >> 9, col = idx & 511;
    const float* src = (row < 64)  ? wq + (size_t)row * 512 + col
                     : (row < 128) ? wk + (size_t)(row - 64) * 512 + col
                                   : wv + (size_t)(row - 128) * 512 + col;
    float4 v = *(const float4*)src;
    float f[4] = {v.x, v.y, v.z, v.w};
    u16x4 o, ol;
#pragma unroll
    for (int e = 0; e < 4; e++) {
        o[e] = f2bf(f[e]);
        ol[e] = f2bf(f[e] - bf2f(o[e]));
    }
    *(u16x4*)(Wb + idx) = o;
    if (row < 128) *(u16x4*)(Wlo + idx) = ol;
}

// ---------------- kernel 1: xT[b][n][c] bf16 hi + lo (transpose of x[b][c][n])
__global__ __launch_bounds__(256) void xpose(const float* __restrict__ x,
                                             ushort_t* __restrict__ xT,
                                             ushort_t* __restrict__ xTlo) {
    __shared__ float lds[64][65];
    const int b = blockIdx.z, c0 = blockIdx.y * 64, n0 = blockIdx.x * 64;
    const int t = threadIdx.x;
    const float* xb = x + (size_t)b * C_ * N_;
#pragma unroll
    for (int i = 0; i < 16; i++) {
        int e = t + i * 256, cc = e >> 6, nn = e & 63;
        lds[cc][nn] = xb[(size_t)(c0 + cc) * N_ + n0 + nn];
    }
    __syncthreads();
    size_t dsto = ((size_t)b * N_ + n0) * C_ + c0;
#pragma unroll
    for (int i = 0; i < 2; i++) {
        int g = t + i * 256, nn = g >> 3, c8 = (g & 7) * 8;
        u16x8 o, ol;
#pragma unroll
        for (int e = 0; e < 8; e++) {
            float f = lds[c8 + e][nn];
            o[e] = f2bf(f);
            ol[e] = f2bf(f - bf2f(o[e]));
        }
        *(u16x8*)(xT + dsto + (size_t)nn * C_ + c8) = o;
        *(u16x8*)(xTlo + dsto + (size_t)nn * C_ + c8) = ol;
    }
}

// ---------------- kernel 2: projections via MFMA.
__global__ __launch_bounds__(256) void proj(const ushort_t* __restrict__ Wb,
                                            const ushort_t* __restrict__ Wlo,
                                            const ushort_t* __restrict__ xT,
                                            const ushort_t* __restrict__ xTlo,
                                            const float* __restrict__ bq,
                                            const float* __restrict__ bk,
                                            const float* __restrict__ bv,
                                            ushort_t* __restrict__ Qt,
                                            ushort_t* __restrict__ Qlo,
                                            ushort_t* __restrict__ Kt,
                                            ushort_t* __restrict__ Klo,
                                            ushort_t* __restrict__ Vb) {
    const int b = blockIdx.z, oy = blockIdx.y, nx = blockIdx.x;
    const int t = threadIdx.x, w = t >> 6, lane = t & 63, lo = lane & 15, hi = lane >> 4;
    const int orow = oy * 64 + w * 16;   // 0..639
    const int n0 = nx * 64;
    const ushort_t* ap = Wb + (size_t)(orow + lo) * 512 + hi * 8;
    const size_t bpo = ((size_t)b * N_ + n0 + lo) * C_ + hi * 8;
    f32x4 acc[4] = {};
    if (orow < 128) {
        const ushort_t* apl = Wlo + (size_t)(orow + lo) * 512 + hi * 8;
        for (int c = 0; c < C_; c += 32) {
            frag8 a  = *(const frag8*)(ap + c);
            frag8 al = *(const frag8*)(apl + c);
#pragma unroll
            for (int nt = 0; nt < 4; nt++) {
                frag8 bb = *(const frag8*)(xT + bpo + (size_t)nt * 16 * C_ + c);
                frag8 bl = *(const frag8*)(xTlo + bpo + (size_t)nt * 16 * C_ + c);
                acc[nt] = __builtin_amdgcn_mfma_f32_16x16x32_bf16(a, bb, acc[nt], 0, 0, 0);
                acc[nt] = __builtin_amdgcn_mfma_f32_16x16x32_bf16(al, bb, acc[nt], 0, 0, 0);
                acc[nt] = __builtin_amdgcn_mfma_f32_16x16x32_bf16(a, bl, acc[nt], 0, 0, 0);
            }
        }
    } else {
        for (int c = 0; c < C_; c += 32) {
            frag8 a = *(const frag8*)(ap + c);
#pragma unroll
            for (int nt = 0; nt < 4; nt++) {
                frag8 bb = *(const frag8*)(xT + bpo + (size_t)nt * 16 * C_ + c);
                acc[nt] = __builtin_amdgcn_mfma_f32_16x16x32_bf16(a, bb, acc[nt], 0, 0, 0);
            }
        }
    }
    float bias[4];
#pragma unroll
    for (int r = 0; r < 4; r++) {
        int o = orow + hi * 4 + r;
        bias[r] = (o < 64) ? bq[o] : (o < 128) ? bk[o - 64] : bv[o - 128];
    }
    if (orow < 128) {
        ushort_t* dsth = (orow < 64 ? Qt : Kt);
        ushort_t* dstl = (orow < 64 ? Qlo : Klo);
        int ob = (orow & 63) + hi * 4;
#pragma unroll
        for (int nt = 0; nt < 4; nt++) {
            int n = n0 + nt * 16 + lo;
            ushort_t h[4], l[4];
#pragma unroll
            for (int r = 0; r < 4; r++) {
                float f = acc[nt][r] + bias[r];
                h[r] = f2bf(f);
                l[r] = f2bf(f - bf2f(h[r]));
            }
            size_t doff = ((size_t)b * N_ + n) * D_ + ob;
            uint_t* dph = (uint_t*)(dsth + doff);
            dph[0] = (uint_t)h[0] | ((uint_t)h[1] << 16);
            dph[1] = (uint_t)h[2] | ((uint_t)h[3] << 16);
            uint_t* dpl = (uint_t*)(dstl + doff);
            dpl[0] = (uint_t)l[0] | ((uint_t)l[1] << 16);
            dpl[1] = (uint_t)l[2] | ((uint_t)l[3] << 16);
        }
    } else {
        int c0 = orow - 128 + hi * 4;
#pragma unroll
        for (int nt = 0; nt < 4; nt++) {
            int n = n0 + nt * 16 + lo;
#pragma unroll
            for (int r = 0; r < 4; r++)
                Vb[((size_t)b * C_ + c0 + r) * N_ + n] = f2bf(acc[nt][r] + bias[r]);
        }
    }
}

// ---------------- kernel 3: softmax stats partials over j-chunks.
// grid (N/64, JC, B), 256 thr. Accumulate 4 score tiles, then one online update per 64 j.
__global__ __launch_bounds__(256, 4) void attn_stats(const ushort_t* __restrict__ Qt,
                                                     const ushort_t* __restrict__ Qlo,
                                                     const ushort_t* __restrict__ Kt,
                                                     const ushort_t* __restrict__ Klo,
                                                     float* __restrict__ mp,
                                                     float* __restrict__ lp) {
    const int b = blockIdx.z, jc = blockIdx.y, i0 = blockIdx.x * 64;
    const int t = threadIdx.x, w = t >> 6, lane = t & 63, lo = lane & 15, hi = lane >> 4;
    const size_t qoff = ((size_t)b * N_ + i0 + w * 16 + lo) * D_ + hi * 8;
    frag8 qh0 = *(const frag8*)(Qt + qoff);
    frag8 qh1 = *(const frag8*)(Qt + qoff + 32);
    frag8 ql0 = *(const frag8*)(Qlo + qoff);
    frag8 ql1 = *(const frag8*)(Qlo + qoff + 32);
    float m[4] = {-INFINITY, -INFINITY, -INFINITY, -INFINITY};
    float l[4] = {0.f, 0.f, 0.f, 0.f};
    const int jbeg = jc * (N_ / JC_), jend = jbeg + N_ / JC_;
    for (int jb = jbeg; jb < jend; jb += 64) {
        f32x4 s[4];
#pragma unroll
        for (int u = 0; u < 4; u++) {
            const size_t koff = ((size_t)b * N_ + jb + u * 16 + lo) * D_ + hi * 8;
            frag8 kh0 = *(const frag8*)(Kt + koff);
            frag8 kh1 = *(const frag8*)(Kt + koff + 32);
            frag8 kl0 = *(const frag8*)(Klo + koff);
            frag8 kl1 = *(const frag8*)(Klo + koff + 32);
            f32x4 sv = {0.f, 0.f, 0.f, 0.f};
            sv = __builtin_amdgcn_mfma_f32_16x16x32_bf16(qh0, kh0, sv, 0, 0, 0);
            sv = __builtin_amdgcn_mfma_f32_16x16x32_bf16(qh1, kh1, sv, 0, 0, 0);
            sv = __builtin_amdgcn_mfma_f32_16x16x32_bf16(ql0, kh0, sv, 0, 0, 0);
            sv = __builtin_amdgcn_mfma_f32_16x16x32_bf16(ql1, kh1, sv, 0, 0, 0);
            sv = __builtin_amdgcn_mfma_f32_16x16x32_bf16(qh0, kl0, sv, 0, 0, 0);
            sv = __builtin_amdgcn_mfma_f32_16x16x32_bf16(qh1, kl1, sv, 0, 0, 0);
            s[u] = sv;
        }
#pragma unroll
        for (int r = 0; r < 4; r++) {
            float s0 = s[0][r] * LOG2E, s1 = s[1][r] * LOG2E;
            float s2 = s[2][r] * LOG2E, s3 = s[3][r] * LOG2E;
            float mx = fmaxf(fmaxf(s0, s1), fmaxf(s2, s3));
            float mn = fmaxf(m[r], mx);
            l[r] = l[r] * exp2f(m[r] - mn)
                 + exp2f(s0 - mn) + exp2f(s1 - mn) + exp2f(s2 - mn) + exp2f(s3 - mn);
            m[r] = mn;
        }
    }
#pragma unroll
    for (int off = 1; off < 16; off <<= 1) {
#pragma unroll
        for (int r = 0; r < 4; r++) {
            float om = __shfl_xor(m[r], off);
            float ol = __shfl_xor(l[r], off);
            float mn = fmaxf(m[r], om);
            l[r] = l[r] * exp2f(m[r] - mn) + ol * exp2f(om - mn);
            m[r] = mn;
        }
    }
    if (lo == 0) {
#pragma unroll
        for (int r = 0; r < 4; r++) {
            int i = i0 + w * 16 + hi * 4 + r;
            size_t o = (size_t)jc * B_ * N_ + b * N_ + i;
            mp[o] = m[r];
            lp[o] = l[r];
        }
    }
}

// ---------------- kernel 3b: merge j-chunk partials
__global__ __launch_bounds__(256) void stats_merge(const float* __restrict__ mp,
                                                   const float* __restrict__ lp,
                                                   float* __restrict__ m2,
                                                   float* __restrict__ li) {
    int idx = blockIdx.x * 256 + threadIdx.x;   // < B*N
    float m = -INFINITY;
#pragma unroll
    for (int jc = 0; jc < JC_; jc++)
        m = fmaxf(m, mp[(size_t)jc * B_ * N_ + idx]);
    float l = 0.f;
#pragma unroll
    for (int jc = 0; jc < JC_; jc++)
        l += lp[(size_t)jc * B_ * N_ + idx] * exp2f(mp[(size_t)jc * B_ * N_ + idx] - m);
    m2[idx] = m;
    li[idx] = 1.0f / l;
}

// ---------------- kernel 4: output. Block = 32 i-rows x full C. 8 waves, j-block 128.
// St = mfma(K,Q) (split-precision) -> P_lds[i][j]; out^T[i][c] = mfma(P, V).
__global__ __launch_bounds__(512, 4) void attn_out(const ushort_t* __restrict__ Qt,
                                                   const ushort_t* __restrict__ Qlo,
                                                   const ushort_t* __restrict__ Kt,
                                                   const ushort_t* __restrict__ Klo,
                                                   const ushort_t* __restrict__ Vb,
                                                   const float* __restrict__ m2,
                                                   const float* __restrict__ li,
                                                   float* __restrict__ out) {
    __shared__ ushort_t Plds[32][136];  // [i][j], stride 272B: balanced 16B-slot classes
    // XCD-aware swizzle: batch b -> XCDs {2b,2b+1}; V[b] (4MB) fits one XCD L2
    const int bid = blockIdx.x;
    const int xcd = bid & 7;
    const int b = xcd >> 1;
    const int i0 = ((bid >> 3) * 2 + (xcd & 1)) * 32;
    const int t = threadIdx.x, w = t >> 6, lane = t & 63, lo = lane & 15, hi = lane >> 4;
    const int jt = w & 3;          // this wave's St j-tile (0..3)
    const int it = w >> 2;         // this wave's St i-tile (0 or 1)

    frag8 qfh[2], qfl[2];
    const int i = i0 + it * 16 + lo;
    const size_t qoff = ((size_t)b * N_ + i) * D_ + hi * 8;
    qfh[0] = *(const frag8*)(Qt + qoff);
    qfh[1] = *(const frag8*)(Qt + qoff + 32);
    qfl[0] = *(const frag8*)(Qlo + qoff);
    qfl[1] = *(const frag8*)(Qlo + qoff + 32);
    const float mv = m2[b * N_ + i];
    const float lv = li[b * N_ + i];

    f32x4 acc[2][4] = {};   // [q i-tile][ct]; c = w*64 + ct*16 + lo
    const ushort_t* Vbase = Vb + ((size_t)b * C_ + w * 64 + lo) * N_;

    for (int jb = 0; jb < N_; jb += 128) {
#pragma unroll
        for (int h = 0; h < 2; h++) {
            const size_t koff = ((size_t)b * N_ + jb + h * 64 + jt * 16 + lo) * D_ + hi * 8;
            frag8 kh0 = *(const frag8*)(Kt + koff);
            frag8 kh1 = *(const frag8*)(Kt + koff + 32);
            frag8 kl0 = *(const frag8*)(Klo + koff);
            frag8 kl1 = *(const frag8*)(Klo + koff + 32);
            f32x4 st = {0.f, 0.f, 0.f, 0.f};
            st = __builtin_amdgcn_mfma_f32_16x16x32_bf16(kh0, qfh[0], st, 0, 0, 0);
            st = __builtin_amdgcn_mfma_f32_16x16x32_bf16(kh1, qfh[1], st, 0, 0, 0);
            st = __builtin_amdgcn_mfma_f32_16x16x32_bf16(kl0, qfh[0], st, 0, 0, 0);
            st = __builtin_amdgcn_mfma_f32_16x16x32_bf16(kl1, qfh[1], st, 0, 0, 0);
            st = __builtin_amdgcn_mfma_f32_16x16x32_bf16(kh0, qfl[0], st, 0, 0, 0);
            st = __builtin_amdgcn_mfma_f32_16x16x32_bf16(kh1, qfl[1], st, 0, 0, 0);
            float p[4];
#pragma unroll
            for (int r = 0; r < 4; r++)
                p[r] = exp2f(st[r] * LOG2E - mv) * lv;
            uint_t pk0 = (uint_t)f2bf(p[0]) | ((uint_t)f2bf(p[1]) << 16);
            uint_t pk1 = (uint_t)f2bf(p[2]) | ((uint_t)f2bf(p[3]) << 16);
            uint_t* dp = (uint_t*)&Plds[it * 16 + lo][h * 64 + jt * 16 + hi * 4];
            dp[0] = pk0; dp[1] = pk1;
        }
        __syncthreads();
#pragma unroll
        for (int js = 0; js < 4; js++) {
            frag8 pa[2];
#pragma unroll
            for (int q = 0; q < 2; q++)
                pa[q] = *(const frag8*)&Plds[q * 16 + lo][js * 32 + hi * 8];
#pragma unroll
            for (int ct = 0; ct < 4; ct++) {
                frag8 vf = *(const frag8*)(Vbase + (size_t)ct * 16 * N_ + jb + js * 32 + hi * 8);
#pragma unroll
                for (int q = 0; q < 2; q++)
                    acc[q][ct] = __builtin_amdgcn_mfma_f32_16x16x32_bf16(pa[q], vf, acc[q][ct], 0, 0, 0);
            }
        }
        __syncthreads();
    }
    // D[m=i][n=c]: row i = i0+q*16+hi*4+r (4 consecutive -> f32x4 store), col c = w*64+ct*16+lo
#pragma unroll
    for (int ct = 0; ct < 4; ct++) {
#pragma unroll
        for (int q = 0; q < 2; q++) {
            float* op = out + ((size_t)b * C_ + w * 64 + ct * 16 + lo) * N_ + i0 + q * 16 + hi * 4;
            *(f32x4*)op = acc[q][ct];
        }
    }
}

extern "C" void kernel_launch(void* const* d_in, const int* in_sizes, int n_in,
                              void* d_out, int out_size, void* d_ws, size_t ws_size,
                              hipStream_t stream) {
    const float* x  = (const float*)d_in[0];
    const float* wq = (const float*)d_in[1];
    const float* bq = (const float*)d_in[2];
    const float* wk = (const float*)d_in[3];
    const float* bk = (const float*)d_in[4];
    const float* wv = (const float*)d_in[5];
    const float* bv = (const float*)d_in[6];
    float* out = (float*)d_out;

    ushort_t* xT   = (ushort_t*)d_ws;                       // B*N*C
    ushort_t* xTlo = xT + (size_t)B_ * N_ * C_;             // B*N*C
    ushort_t* Wb   = xTlo + (size_t)B_ * N_ * C_;           // 640*512
    ushort_t* Wlo  = Wb + (size_t)OROWS * 512;              // 128*512
    ushort_t* Qt   = Wlo + (size_t)128 * 512;               // B*N*64
    ushort_t* Qlo  = Qt + (size_t)B_ * N_ * D_;             // B*N*64
    ushort_t* Kt   = Qlo + (size_t)B_ * N_ * D_;            // B*N*64
    ushort_t* Klo  = Kt + (size_t)B_ * N_ * D_;             // B*N*64
    ushort_t* Vb   = Klo + (size_t)B_ * N_ * D_;            // B*C*N
    float*    m2   = (float*)(Vb + (size_t)B_ * C_ * N_);   // B*N
    float*    li   = m2 + (size_t)B_ * N_;                  // B*N
    float*    mp   = li + (size_t)B_ * N_;                  // JC*B*N
    float*    lp   = mp + (size_t)JC_ * B_ * N_;            // JC*B*N

    convw<<<dim3(OROWS * 512 / (256 * 4)), 256, 0, stream>>>(wq, wk, wv, Wb, Wlo);
    xpose<<<dim3(N_ / 64, C_ / 64, B_), 256, 0, stream>>>(x, xT, xTlo);
    proj<<<dim3(N_ / 64, 10, B_), 256, 0, stream>>>(Wb, Wlo, xT, xTlo, bq, bk, bv,
                                                    Qt, Qlo, Kt, Klo, Vb);
    attn_stats<<<dim3(N_ / 64, JC_, B_), 256, 0, stream>>>(Qt, Qlo, Kt, Klo, mp, lp);
    stats_merge<<<dim3(B_ * N_ / 256), 256, 0, stream>>>(mp, lp, m2, li);
    attn_out<<<dim3(B_ * N_ / 32), 512, 0, stream>>>(Qt, Qlo, Kt, Klo, Vb, m2, li, out);
}

// Round 4
// 524.946 us; speedup vs baseline: 1.3189x; 1.3189x over previous
//
#include <hip/hip_runtime.h>
#include <hip/hip_bf16.h>

typedef unsigned short ushort_t;
typedef unsigned int   uint_t;

typedef short    frag8  __attribute__((ext_vector_type(8)));   // 8 bf16 (4 VGPRs)
typedef float    f32x4  __attribute__((ext_vector_type(4)));
typedef ushort_t u16x8  __attribute__((ext_vector_type(8)));
typedef ushort_t u16x4  __attribute__((ext_vector_type(4)));

#define LOG2E 1.44269504088896340736f

constexpr int B_ = 4;
constexpr int C_ = 512;
constexpr int N_ = 4096;
constexpr int D_ = 64;    // CQK
constexpr int OROWS = 640; // 64 q + 64 k + 512 v
constexpr int JC_ = 8;     // j-chunks for attn_stats

__device__ __forceinline__ ushort_t f2bf(float f) {
    unsigned int x = __float_as_uint(f);
    unsigned int r = x + 0x7fffu + ((x >> 16) & 1u);
    return (ushort_t)(r >> 16);
}
__device__ __forceinline__ float bf2f(ushort_t h) {
    return __uint_as_float(((uint_t)h) << 16);
}

// raw barrier: LDS-visibility only; global loads stay in flight (no vmcnt drain)
__device__ __forceinline__ void pbar() {
    asm volatile("s_waitcnt lgkmcnt(0)" ::: "memory");
    __builtin_amdgcn_s_barrier();
    asm volatile("" ::: "memory");
}

// ---------------- kernel 0: pack weights to bf16 hi (+ lo residual for q/k rows)
__global__ __launch_bounds__(256) void convw(const float* __restrict__ wq,
                                             const float* __restrict__ wk,
                                             const float* __restrict__ wv,
                                             ushort_t* __restrict__ Wb,
                                             ushort_t* __restrict__ Wlo) {
    int idx = (blockIdx.x * 256 + threadIdx.x) * 4;
    int row = idx >> 9, col = idx & 511;
    const float* src = (row < 64)  ? wq + (size_t)row * 512 + col
                     : (row < 128) ? wk + (size_t)(row - 64) * 512 + col
                                   : wv + (size_t)(row - 128) * 512 + col;
    float4 v = *(const float4*)src;
    float f[4] = {v.x, v.y, v.z, v.w};
    u16x4 o, ol;
#pragma unroll
    for (int e = 0; e < 4; e++) {
        o[e] = f2bf(f[e]);
        ol[e] = f2bf(f[e] - bf2f(o[e]));
    }
    *(u16x4*)(Wb + idx) = o;
    if (row < 128) *(u16x4*)(Wlo + idx) = ol;
}

// ---------------- kernel 1: xT[b][n][c] bf16 hi + lo (transpose of x[b][c][n])
__global__ __launch_bounds__(256) void xpose(const float* __restrict__ x,
                                             ushort_t* __restrict__ xT,
                                             ushort_t* __restrict__ xTlo) {
    __shared__ float lds[64][65];
    const int b = blockIdx.z, c0 = blockIdx.y * 64, n0 = blockIdx.x * 64;
    const int t = threadIdx.x;
    const float* xb = x + (size_t)b * C_ * N_;
#pragma unroll
    for (int i = 0; i < 16; i++) {
        int e = t + i * 256, cc = e >> 6, nn = e & 63;
        lds[cc][nn] = xb[(size_t)(c0 + cc) * N_ + n0 + nn];
    }
    __syncthreads();
    size_t dsto = ((size_t)b * N_ + n0) * C_ + c0;
#pragma unroll
    for (int i = 0; i < 2; i++) {
        int g = t + i * 256, nn = g >> 3, c8 = (g & 7) * 8;
        u16x8 o, ol;
#pragma unroll
        for (int e = 0; e < 8; e++) {
            float f = lds[c8 + e][nn];
            o[e] = f2bf(f);
            ol[e] = f2bf(f - bf2f(o[e]));
        }
        *(u16x8*)(xT + dsto + (size_t)nn * C_ + c8) = o;
        *(u16x8*)(xTlo + dsto + (size_t)nn * C_ + c8) = ol;
    }
}

// ---------------- kernel 2: projections via MFMA.
__global__ __launch_bounds__(256) void proj(const ushort_t* __restrict__ Wb,
                                            const ushort_t* __restrict__ Wlo,
                                            const ushort_t* __restrict__ xT,
                                            const ushort_t* __restrict__ xTlo,
                                            const float* __restrict__ bq,
                                            const float* __restrict__ bk,
                                            const float* __restrict__ bv,
                                            ushort_t* __restrict__ Qt,
                                            ushort_t* __restrict__ Qlo,
                                            ushort_t* __restrict__ Kt,
                                            ushort_t* __restrict__ Klo,
                                            ushort_t* __restrict__ Vb) {
    const int b = blockIdx.z, oy = blockIdx.y, nx = blockIdx.x;
    const int t = threadIdx.x, w = t >> 6, lane = t & 63, lo = lane & 15, hi = lane >> 4;
    const int orow = oy * 64 + w * 16;   // 0..639
    const int n0 = nx * 64;
    const ushort_t* ap = Wb + (size_t)(orow + lo) * 512 + hi * 8;
    const size_t bpo = ((size_t)b * N_ + n0 + lo) * C_ + hi * 8;
    f32x4 acc[4] = {};
    if (orow < 128) {
        const ushort_t* apl = Wlo + (size_t)(orow + lo) * 512 + hi * 8;
        for (int c = 0; c < C_; c += 32) {
            frag8 a  = *(const frag8*)(ap + c);
            frag8 al = *(const frag8*)(apl + c);
#pragma unroll
            for (int nt = 0; nt < 4; nt++) {
                frag8 bb = *(const frag8*)(xT + bpo + (size_t)nt * 16 * C_ + c);
                frag8 bl = *(const frag8*)(xTlo + bpo + (size_t)nt * 16 * C_ + c);
                acc[nt] = __builtin_amdgcn_mfma_f32_16x16x32_bf16(a, bb, acc[nt], 0, 0, 0);
                acc[nt] = __builtin_amdgcn_mfma_f32_16x16x32_bf16(al, bb, acc[nt], 0, 0, 0);
                acc[nt] = __builtin_amdgcn_mfma_f32_16x16x32_bf16(a, bl, acc[nt], 0, 0, 0);
            }
        }
    } else {
        for (int c = 0; c < C_; c += 32) {
            frag8 a = *(const frag8*)(ap + c);
#pragma unroll
            for (int nt = 0; nt < 4; nt++) {
                frag8 bb = *(const frag8*)(xT + bpo + (size_t)nt * 16 * C_ + c);
                acc[nt] = __builtin_amdgcn_mfma_f32_16x16x32_bf16(a, bb, acc[nt], 0, 0, 0);
            }
        }
    }
    float bias[4];
#pragma unroll
    for (int r = 0; r < 4; r++) {
        int o = orow + hi * 4 + r;
        bias[r] = (o < 64) ? bq[o] : (o < 128) ? bk[o - 64] : bv[o - 128];
    }
    if (orow < 128) {
        ushort_t* dsth = (orow < 64 ? Qt : Kt);
        ushort_t* dstl = (orow < 64 ? Qlo : Klo);
        int ob = (orow & 63) + hi * 4;
#pragma unroll
        for (int nt = 0; nt < 4; nt++) {
            int n = n0 + nt * 16 + lo;
            ushort_t h[4], l[4];
#pragma unroll
            for (int r = 0; r < 4; r++) {
                float f = acc[nt][r] + bias[r];
                h[r] = f2bf(f);
                l[r] = f2bf(f - bf2f(h[r]));
            }
            size_t doff = ((size_t)b * N_ + n) * D_ + ob;
            uint_t* dph = (uint_t*)(dsth + doff);
            dph[0] = (uint_t)h[0] | ((uint_t)h[1] << 16);
            dph[1] = (uint_t)h[2] | ((uint_t)h[3] << 16);
            uint_t* dpl = (uint_t*)(dstl + doff);
            dpl[0] = (uint_t)l[0] | ((uint_t)l[1] << 16);
            dpl[1] = (uint_t)l[2] | ((uint_t)l[3] << 16);
        }
    } else {
        int c0 = orow - 128 + hi * 4;
#pragma unroll
        for (int nt = 0; nt < 4; nt++) {
            int n = n0 + nt * 16 + lo;
#pragma unroll
            for (int r = 0; r < 4; r++)
                Vb[((size_t)b * C_ + c0 + r) * N_ + n] = f2bf(acc[nt][r] + bias[r]);
        }
    }
}

// ---------------- kernel 3: softmax stats partials over j-chunks.
__global__ __launch_bounds__(256, 4) void attn_stats(const ushort_t* __restrict__ Qt,
                                                     const ushort_t* __restrict__ Qlo,
                                                     const ushort_t* __restrict__ Kt,
                                                     const ushort_t* __restrict__ Klo,
                                                     float* __restrict__ mp,
                                                     float* __restrict__ lp) {
    const int b = blockIdx.z, jc = blockIdx.y, i0 = blockIdx.x * 64;
    const int t = threadIdx.x, w = t >> 6, lane = t & 63, lo = lane & 15, hi = lane >> 4;
    const size_t qoff = ((size_t)b * N_ + i0 + w * 16 + lo) * D_ + hi * 8;
    frag8 qh0 = *(const frag8*)(Qt + qoff);
    frag8 qh1 = *(const frag8*)(Qt + qoff + 32);
    frag8 ql0 = *(const frag8*)(Qlo + qoff);
    frag8 ql1 = *(const frag8*)(Qlo + qoff + 32);
    float m[4] = {-INFINITY, -INFINITY, -INFINITY, -INFINITY};
    float l[4] = {0.f, 0.f, 0.f, 0.f};
    const int jbeg = jc * (N_ / JC_), jend = jbeg + N_ / JC_;
    for (int jb = jbeg; jb < jend; jb += 64) {
        f32x4 s[4];
#pragma unroll
        for (int u = 0; u < 4; u++) {
            const size_t koff = ((size_t)b * N_ + jb + u * 16 + lo) * D_ + hi * 8;
            frag8 kh0 = *(const frag8*)(Kt + koff);
            frag8 kh1 = *(const frag8*)(Kt + koff + 32);
            frag8 kl0 = *(const frag8*)(Klo + koff);
            frag8 kl1 = *(const frag8*)(Klo + koff + 32);
            f32x4 sa = {0.f, 0.f, 0.f, 0.f};
            f32x4 sb = {0.f, 0.f, 0.f, 0.f};
            sa = __builtin_amdgcn_mfma_f32_16x16x32_bf16(qh0, kh0, sa, 0, 0, 0);
            sb = __builtin_amdgcn_mfma_f32_16x16x32_bf16(qh1, kh1, sb, 0, 0, 0);
            sa = __builtin_amdgcn_mfma_f32_16x16x32_bf16(ql0, kh0, sa, 0, 0, 0);
            sb = __builtin_amdgcn_mfma_f32_16x16x32_bf16(ql1, kh1, sb, 0, 0, 0);
            sa = __builtin_amdgcn_mfma_f32_16x16x32_bf16(qh0, kl0, sa, 0, 0, 0);
            sb = __builtin_amdgcn_mfma_f32_16x16x32_bf16(qh1, kl1, sb, 0, 0, 0);
            s[u] = sa + sb;
        }
#pragma unroll
        for (int r = 0; r < 4; r++) {
            float s0 = s[0][r] * LOG2E, s1 = s[1][r] * LOG2E;
            float s2 = s[2][r] * LOG2E, s3 = s[3][r] * LOG2E;
            float mx = fmaxf(fmaxf(s0, s1), fmaxf(s2, s3));
            float mn = fmaxf(m[r], mx);
            l[r] = l[r] * exp2f(m[r] - mn)
                 + exp2f(s0 - mn) + exp2f(s1 - mn) + exp2f(s2 - mn) + exp2f(s3 - mn);
            m[r] = mn;
        }
    }
#pragma unroll
    for (int off = 1; off < 16; off <<= 1) {
#pragma unroll
        for (int r = 0; r < 4; r++) {
            float om = __shfl_xor(m[r], off);
            float ol = __shfl_xor(l[r], off);
            float mn = fmaxf(m[r], om);
            l[r] = l[r] * exp2f(m[r] - mn) + ol * exp2f(om - mn);
            m[r] = mn;
        }
    }
    if (lo == 0) {
#pragma unroll
        for (int r = 0; r < 4; r++) {
            int i = i0 + w * 16 + hi * 4 + r;
            size_t o = (size_t)jc * B_ * N_ + b * N_ + i;
            mp[o] = m[r];
            lp[o] = l[r];
        }
    }
}

// ---------------- kernel 3b: merge j-chunk partials
__global__ __launch_bounds__(256) void stats_merge(const float* __restrict__ mp,
                                                   const float* __restrict__ lp,
                                                   float* __restrict__ m2,
                                                   float* __restrict__ li) {
    int idx = blockIdx.x * 256 + threadIdx.x;   // < B*N
    float m = -INFINITY;
#pragma unroll
    for (int jc = 0; jc < JC_; jc++)
        m = fmaxf(m, mp[(size_t)jc * B_ * N_ + idx]);
    float l = 0.f;
#pragma unroll
    for (int jc = 0; jc < JC_; jc++)
        l += lp[(size_t)jc * B_ * N_ + idx] * exp2f(mp[(size_t)jc * B_ * N_ + idx] - m);
    m2[idx] = m;
    li[idx] = 1.0f / l;
}

// ---------------- kernel 4: output. Block = 64 i-rows x full C. 8 waves.
// Software-pipelined: double-buffered P in LDS, ONE raw barrier per 64-j step,
// K register-double-buffered one step ahead, V issued at body start.
// Body s: V(s) loads | K(s+2) loads | QK(s+1)->buf[(s+1)&1] | PV(s)<-buf[s&1] | pbar.
__global__ __launch_bounds__(512, 2) void attn_out(const ushort_t* __restrict__ Qt,
                                                   const ushort_t* __restrict__ Qlo,
                                                   const ushort_t* __restrict__ Kt,
                                                   const ushort_t* __restrict__ Klo,
                                                   const ushort_t* __restrict__ Vb,
                                                   const float* __restrict__ m2,
                                                   const float* __restrict__ li,
                                                   float* __restrict__ out) {
    __shared__ ushort_t Plds[2][64][72];  // [buf][i][j], 144B stride
    // XCD-aware swizzle: batch b -> XCDs {2b,2b+1}; V[b] (4MB) ~fits one XCD L2
    const int bid = blockIdx.x;           // 256 blocks = B * N/64
    const int xcd = bid & 7;
    const int b = xcd >> 1;
    const int i0 = ((bid >> 3) * 2 + (xcd & 1)) * 64;
    const int t = threadIdx.x, w = t >> 6, lane = t & 63, lo = lane & 15, hi = lane >> 4;
    const int jt = w & 3;            // QK j-subtile (0..3)
    const int itb = (w >> 2) * 2;    // QK i-subtile base (0 or 2)
    const size_t bN = (size_t)b * N_;

    frag8 qfh[2][2], qfl[2][2];
    float mv[2], lv[2];
#pragma unroll
    for (int q = 0; q < 2; q++) {
        const int i = i0 + (itb + q) * 16 + lo;
        const size_t qoff = (bN + i) * D_ + hi * 8;
        qfh[q][0] = *(const frag8*)(Qt + qoff);
        qfh[q][1] = *(const frag8*)(Qt + qoff + 32);
        qfl[q][0] = *(const frag8*)(Qlo + qoff);
        qfl[q][1] = *(const frag8*)(Qlo + qoff + 32);
        mv[q] = m2[bN + i];
        lv[q] = li[bN + i];
    }

    f32x4 acc[4][4] = {};   // [it][ct]; c = w*64 + ct*16 + lo, i = i0 + it*16 + (hi*4+r)
    const ushort_t* Vbase = Vb + ((size_t)b * C_ + w * 64 + lo) * N_;

    frag8 Ah0, Ah1, Al0, Al1, Bh0, Bh1, Bl0, Bl1;

#define LOADK(Ph0, Ph1, Pl0, Pl1, jb) do {                                   \
    const size_t ko = (bN + (jb) + jt * 16 + lo) * D_ + hi * 8;              \
    Ph0 = *(const frag8*)(Kt + ko);  Ph1 = *(const frag8*)(Kt + ko + 32);    \
    Pl0 = *(const frag8*)(Klo + ko); Pl1 = *(const frag8*)(Klo + ko + 32);   \
} while (0)

#define QKPH(Ph0, Ph1, Pl0, Pl1, bufi) do {                                  \
    _Pragma("unroll")                                                        \
    for (int q = 0; q < 2; q++) {                                            \
        f32x4 sa = {0.f, 0.f, 0.f, 0.f};                                     \
        f32x4 sb = {0.f, 0.f, 0.f, 0.f};                                     \
        sa = __builtin_amdgcn_mfma_f32_16x16x32_bf16(Ph0, qfh[q][0], sa, 0, 0, 0); \
        sb = __builtin_amdgcn_mfma_f32_16x16x32_bf16(Ph1, qfh[q][1], sb, 0, 0, 0); \
        sa = __builtin_amdgcn_mfma_f32_16x16x32_bf16(Pl0, qfh[q][0], sa, 0, 0, 0); \
        sb = __builtin_amdgcn_mfma_f32_16x16x32_bf16(Pl1, qfh[q][1], sb, 0, 0, 0); \
        sa = __builtin_amdgcn_mfma_f32_16x16x32_bf16(Ph0, qfl[q][0], sa, 0, 0, 0); \
        sb = __builtin_amdgcn_mfma_f32_16x16x32_bf16(Ph1, qfl[q][1], sb, 0, 0, 0); \
        f32x4 st = sa + sb;                                                  \
        float p0 = exp2f(st[0] * LOG2E - mv[q]) * lv[q];                     \
        float p1 = exp2f(st[1] * LOG2E - mv[q]) * lv[q];                     \
        float p2 = exp2f(st[2] * LOG2E - mv[q]) * lv[q];                     \
        float p3 = exp2f(st[3] * LOG2E - mv[q]) * lv[q];                     \
        uint_t pk0 = (uint_t)f2bf(p0) | ((uint_t)f2bf(p1) << 16);            \
        uint_t pk1 = (uint_t)f2bf(p2) | ((uint_t)f2bf(p3) << 16);            \
        uint_t* dp = (uint_t*)&Plds[bufi][(itb + q) * 16 + lo][jt * 16 + hi * 4]; \
        dp[0] = pk0; dp[1] = pk1;                                            \
    }                                                                        \
} while (0)

#define LOADV(vf, jb) do {                                                   \
    _Pragma("unroll")                                                        \
    for (int js = 0; js < 2; js++)                                           \
        _Pragma("unroll")                                                    \
        for (int ct = 0; ct < 4; ct++)                                       \
            vf[js][ct] = *(const frag8*)(Vbase + (size_t)ct * 16 * N_ + (jb) + js * 32 + hi * 8); \
} while (0)

#define PVPH(bufi, vf) do {                                                  \
    frag8 pa[2][4];                                                          \
    _Pragma("unroll")                                                        \
    for (int js = 0; js < 2; js++)                                           \
        _Pragma("unroll")                                                    \
        for (int it = 0; it < 4; it++)                                       \
            pa[js][it] = *(const frag8*)&Plds[bufi][it * 16 + lo][js * 32 + hi * 8]; \
    __builtin_amdgcn_s_setprio(1);                                           \
    _Pragma("unroll")                                                        \
    for (int js = 0; js < 2; js++)                                           \
        _Pragma("unroll")                                                    \
        for (int ct = 0; ct < 4; ct++)                                       \
            _Pragma("unroll")                                                \
            for (int it = 0; it < 4; it++)                                   \
                acc[it][ct] = __builtin_amdgcn_mfma_f32_16x16x32_bf16(pa[js][it], vf[js][ct], acc[it][ct], 0, 0, 0); \
    __builtin_amdgcn_s_setprio(0);                                           \
} while (0)

#define BODY(s, KC0, KC1, KC2, KC3, KN0, KN1, KN2, KN3, DOLK) do {           \
    const int jb_ = (s) * 64;                                                \
    frag8 vf[2][4];                                                          \
    LOADV(vf, jb_);                                                          \
    if (DOLK) LOADK(KN0, KN1, KN2, KN3, jb_ + 128);                          \
    QKPH(KC0, KC1, KC2, KC3, ((s) + 1) & 1);                                 \
    PVPH((s) & 1, vf);                                                       \
    pbar();                                                                  \
} while (0)

    // prologue: QK(0) -> buf0; preload K(1) into A
    LOADK(Ah0, Ah1, Al0, Al1, 0);
    QKPH(Ah0, Ah1, Al0, Al1, 0);
    LOADK(Ah0, Ah1, Al0, Al1, 64);
    pbar();

    for (int s2 = 0; s2 < 31; s2++) {
        BODY(2 * s2,     Ah0, Ah1, Al0, Al1, Bh0, Bh1, Bl0, Bl1, 1);
        BODY(2 * s2 + 1, Bh0, Bh1, Bl0, Bl1, Ah0, Ah1, Al0, Al1, 1);
    }
    BODY(62, Ah0, Ah1, Al0, Al1, Bh0, Bh1, Bl0, Bl1, 0);
    {   // epilogue: PV(63) from buf[1]
        frag8 vf[2][4];
        LOADV(vf, 63 * 64);
        PVPH(1, vf);
    }

#undef LOADK
#undef QKPH
#undef LOADV
#undef PVPH
#undef BODY

    // store: out[c][i], i = i0+it*16+hi*4+r (f32x4), c = w*64+ct*16+lo
#pragma unroll
    for (int ct = 0; ct < 4; ct++) {
#pragma unroll
        for (int it = 0; it < 4; it++) {
            float* op = out + ((size_t)b * C_ + w * 64 + ct * 16 + lo) * N_ + i0 + it * 16 + hi * 4;
            *(f32x4*)op = acc[it][ct];
        }
    }
}

extern "C" void kernel_launch(void* const* d_in, const int* in_sizes, int n_in,
                              void* d_out, int out_size, void* d_ws, size_t ws_size,
                              hipStream_t stream) {
    const float* x  = (const float*)d_in[0];
    const float* wq = (const float*)d_in[1];
    const float* bq = (const float*)d_in[2];
    const float* wk = (const float*)d_in[3];
    const float* bk = (const float*)d_in[4];
    const float* wv = (const float*)d_in[5];
    const float* bv = (const float*)d_in[6];
    float* out = (float*)d_out;

    ushort_t* xT   = (ushort_t*)d_ws;                       // B*N*C
    ushort_t* xTlo = xT + (size_t)B_ * N_ * C_;             // B*N*C
    ushort_t* Wb   = xTlo + (size_t)B_ * N_ * C_;           // 640*512
    ushort_t* Wlo  = Wb + (size_t)OROWS * 512;              // 128*512
    ushort_t* Qt   = Wlo + (size_t)128 * 512;               // B*N*64
    ushort_t* Qlo  = Qt + (size_t)B_ * N_ * D_;             // B*N*64
    ushort_t* Kt   = Qlo + (size_t)B_ * N_ * D_;            // B*N*64
    ushort_t* Klo  = Kt + (size_t)B_ * N_ * D_;             // B*N*64
    ushort_t* Vb   = Klo + (size_t)B_ * N_ * D_;            // B*C*N
    float*    m2   = (float*)(Vb + (size_t)B_ * C_ * N_);   // B*N
    float*    li   = m2 + (size_t)B_ * N_;                  // B*N
    float*    mp   = li + (size_t)B_ * N_;                  // JC*B*N
    float*    lp   = mp + (size_t)JC_ * B_ * N_;            // JC*B*N

    convw<<<dim3(OROWS * 512 / (256 * 4)), 256, 0, stream>>>(wq, wk, wv, Wb, Wlo);
    xpose<<<dim3(N_ / 64, C_ / 64, B_), 256, 0, stream>>>(x, xT, xTlo);
    proj<<<dim3(N_ / 64, 10, B_), 256, 0, stream>>>(Wb, Wlo, xT, xTlo, bq, bk, bv,
                                                    Qt, Qlo, Kt, Klo, Vb);
    attn_stats<<<dim3(N_ / 64, JC_, B_), 256, 0, stream>>>(Qt, Qlo, Kt, Klo, mp, lp);
    stats_merge<<<dim3(B_ * N_ / 256), 256, 0, stream>>>(mp, lp, m2, li);
    attn_out<<<dim3(B_ * N_ / 64), 512, 0, stream>>>(Qt, Qlo, Kt, Klo, Vb, m2, li, out);
}